// Round 4
// baseline (5541.522 us; speedup 1.0000x reference)
//
#include <hip/hip_runtime.h>
#include <hip/hip_bf16.h>
#include <math.h>

// ---------------- CSR build ----------------

__global__ __launch_bounds__(256) void k_hist(const int* __restrict__ dst, int* __restrict__ cnt, int E) {
    int i = blockIdx.x * blockDim.x + threadIdx.x;
    if (i < E) atomicAdd(&cnt[dst[i]], 1);
}

__global__ __launch_bounds__(256) void k_scanA(const int* __restrict__ cnt, int* __restrict__ bsum, int N) {
    __shared__ int s[256];
    int t = threadIdx.x;
    int i = blockIdx.x * 256 + t;
    s[t] = (i < N) ? cnt[i] : 0;
    __syncthreads();
    for (int off = 128; off > 0; off >>= 1) {
        if (t < off) s[t] += s[t + off];
        __syncthreads();
    }
    if (t == 0) bsum[blockIdx.x] = s[0];
}

__global__ __launch_bounds__(512) void k_scanB(int* __restrict__ bsum, int B) {
    __shared__ int s[512];
    int t = threadIdx.x;
    int v = (t < B) ? bsum[t] : 0;
    s[t] = v;
    __syncthreads();
    for (int off = 1; off < 512; off <<= 1) {
        int x = (t >= off) ? s[t - off] : 0;
        __syncthreads();
        s[t] += x;
        __syncthreads();
    }
    if (t < B) bsum[t] = s[t] - v;   // exclusive
}

__global__ __launch_bounds__(256) void k_scanC(const int* __restrict__ cnt, const int* __restrict__ bsum,
                                               int* __restrict__ row_off, int* __restrict__ cursor,
                                               float* __restrict__ dinv, int N, int E) {
    __shared__ int s[256];
    int t = threadIdx.x;
    int i = blockIdx.x * 256 + t;
    int v = (i < N) ? cnt[i] : 0;
    s[t] = v;
    __syncthreads();
    for (int off = 1; off < 256; off <<= 1) {
        int x = (t >= off) ? s[t - off] : 0;
        __syncthreads();
        s[t] += x;
        __syncthreads();
    }
    if (i < N) {
        int excl = bsum[blockIdx.x] + s[t] - v;
        row_off[i] = excl;
        cursor[i]  = excl;
        dinv[i]    = rsqrtf((float)(v > 1 ? v : 1));
    }
    if (i == 0) row_off[N] = E;
}

__global__ __launch_bounds__(256) void k_scatter(const int* __restrict__ src, const int* __restrict__ dst,
                                                 int* __restrict__ cursor, int* __restrict__ csr, int E) {
    int i = blockIdx.x * blockDim.x + threadIdx.x;
    if (i < E) {
        int d = dst[i];
        int pos = atomicAdd(&cursor[d], 1);
        csr[pos] = src[i];
    }
}

// ---------------- Chebyshev aggregation: out = alpha * (dinv[n] * sum_j X[j]*dinv[j]) + beta * Z[n] ----------------

template <int D>
__global__ __launch_bounds__(256) void k_aggr(const float* __restrict__ X, const float* __restrict__ Z,
                                              const float* __restrict__ dinv,
                                              const int* __restrict__ row_off, const int* __restrict__ csr,
                                              float* __restrict__ out, float alpha, float beta, int N) {
    int t = blockIdx.x * blockDim.x + threadIdx.x;
    int node = t / D;
    int d = t % D;
    if (node >= N) return;
    int beg = row_off[node], end = row_off[node + 1];
    float a0 = 0.f, a1 = 0.f, a2 = 0.f, a3 = 0.f;
    int j = beg;
    for (; j + 3 < end; j += 4) {
        int s0 = csr[j], s1 = csr[j + 1], s2 = csr[j + 2], s3 = csr[j + 3];
        a0 += X[s0 * D + d] * dinv[s0];
        a1 += X[s1 * D + d] * dinv[s1];
        a2 += X[s2 * D + d] * dinv[s2];
        a3 += X[s3 * D + d] * dinv[s3];
    }
    for (; j < end; ++j) {
        int s = csr[j];
        a0 += X[s * D + d] * dinv[s];
    }
    float acc = (a0 + a1) + (a2 + a3);
    float v = alpha * dinv[node] * acc;
    if (Z) v += beta * Z[node * D + d];
    out[node * D + d] = v;
}

// ---------------- Cheb matmul: out = relu(b + X0@W[0] + X1@W[1] + X2@W[2]), W[k][i][o] ----------------
// Grid-stride, weights staged once per block. ILP design: 2 nodes per wave-iter,
// 6 independent accumulator chains (3 per node, one per W_k), next pair's X rows
// prefetched before the inner loop so global latency overlaps FMA issue.

template <int K>
__global__ __launch_bounds__(256, 3) void k_cheb_mm(const float* __restrict__ X0, const float* __restrict__ X1,
                                                    const float* __restrict__ X2, const float* __restrict__ W,
                                                    const float* __restrict__ b, float* __restrict__ out, int N) {
    __shared__ float Ws[3 * K * 64];
    int t = threadIdx.x;
    for (int idx = t; idx < 3 * K * 64; idx += 256) Ws[idx] = W[idx];
    __syncthreads();
    int wave = t >> 6, lane = t & 63;
    int gw = blockIdx.x * 4 + wave;
    int stride = gridDim.x * 4 * 2;        // node-pairs per sweep
    float bias = b[lane];

    int n = gw * 2;
    if (n >= N) return;

    // current pair registers
    float ca0 = 0.f, ca1 = 0.f, ca2 = 0.f, cb0 = 0.f, cb1 = 0.f, cb2 = 0.f;
    {
        int m1 = (n + 1 < N) ? n + 1 : N - 1;
        if (lane < K) {
            ca0 = X0[n * K + lane];  ca1 = X1[n * K + lane];  ca2 = X2[n * K + lane];
            cb0 = X0[m1 * K + lane]; cb1 = X1[m1 * K + lane]; cb2 = X2[m1 * K + lane];
        }
    }

    while (n < N) {
        int nn = n + stride;
        // prefetch next pair (clamped; values unused if OOB)
        float pa0 = 0.f, pa1 = 0.f, pa2 = 0.f, pb0 = 0.f, pb1 = 0.f, pb2 = 0.f;
        {
            int q0 = (nn < N) ? nn : N - 1;
            int q1 = (nn + 1 < N) ? nn + 1 : N - 1;
            if (lane < K) {
                pa0 = X0[q0 * K + lane]; pa1 = X1[q0 * K + lane]; pa2 = X2[q0 * K + lane];
                pb0 = X0[q1 * K + lane]; pb1 = X1[q1 * K + lane]; pb2 = X2[q1 * K + lane];
            }
        }
        float aa0 = 0.f, aa1 = 0.f, aa2 = 0.f, ab0 = 0.f, ab1 = 0.f, ab2 = 0.f;
#pragma unroll
        for (int i = 0; i < K; ++i) {
            float w0 = Ws[i * 64 + lane];
            float w1 = Ws[(K + i) * 64 + lane];
            float w2 = Ws[(2 * K + i) * 64 + lane];
            aa0 += __shfl(ca0, i) * w0; ab0 += __shfl(cb0, i) * w0;
            aa1 += __shfl(ca1, i) * w1; ab1 += __shfl(cb1, i) * w1;
            aa2 += __shfl(ca2, i) * w2; ab2 += __shfl(cb2, i) * w2;
        }
        out[n * 64 + lane] = fmaxf(bias + (aa0 + aa1) + aa2, 0.f);
        if (n + 1 < N) out[(n + 1) * 64 + lane] = fmaxf(bias + (ab0 + ab1) + ab2, 0.f);
        n = nn;
        ca0 = pa0; ca1 = pa1; ca2 = pa2; cb0 = pb0; cb1 = pb1; cb2 = pb2;
    }
}

// ---------------- EdgeConv stage 1: m = X@Wt ; p = X@(Wt+Wp) + bt + bp ----------------
// Same ILP structure; stages Wt and (Wt+Wp) so each MAC-pair is 2 FMAs.

__global__ __launch_bounds__(256, 4) void k_e1(const float* __restrict__ X, const float* __restrict__ Wt,
                                               const float* __restrict__ Wp, const float* __restrict__ bt,
                                               const float* __restrict__ bp, float* __restrict__ m,
                                               float* __restrict__ pbuf, int N) {
    __shared__ float Wts[64 * 64];
    __shared__ float Wss[64 * 64];   // Wt + Wp
    int t = threadIdx.x;
    for (int idx = t; idx < 4096; idx += 256) {
        float wt = Wt[idx];
        Wts[idx] = wt;
        Wss[idx] = wt + Wp[idx];
    }
    __syncthreads();
    int wave = t >> 6, lane = t & 63;
    int gw = blockIdx.x * 4 + wave;
    int stride = gridDim.x * 4 * 2;
    float bias = bt[lane] + bp[lane];

    int n = gw * 2;
    if (n >= N) return;

    float cva, cvb;
    {
        int m1 = (n + 1 < N) ? n + 1 : N - 1;
        cva = X[n * 64 + lane];
        cvb = X[m1 * 64 + lane];
    }

    while (n < N) {
        int nn = n + stride;
        float pva = 0.f, pvb = 0.f;
        {
            int q0 = (nn < N) ? nn : N - 1;
            int q1 = (nn + 1 < N) ? nn + 1 : N - 1;
            pva = X[q0 * 64 + lane];
            pvb = X[q1 * 64 + lane];
        }
        float ama = 0.f, apa = 0.f, amb = 0.f, apb = 0.f;
#pragma unroll
        for (int i = 0; i < 64; ++i) {
            float wt = Wts[i * 64 + lane];
            float ws = Wss[i * 64 + lane];
            float xa = __shfl(cva, i);
            float xb = __shfl(cvb, i);
            ama += xa * wt; apa += xa * ws;
            amb += xb * wt; apb += xb * ws;
        }
        m[n * 64 + lane] = ama;
        pbuf[n * 64 + lane] = apa + bias;
        if (n + 1 < N) {
            m[(n + 1) * 64 + lane] = amb;
            pbuf[(n + 1) * 64 + lane] = apb + bias;
        }
        n = nn;
        cva = pva; cvb = pvb;
    }
}

// ---------------- EdgeConv stage 2: out = relu(p[n] + max_j(-m[src_j])), 0 if no in-edges ----------------

__global__ __launch_bounds__(256) void k_e2(const float* __restrict__ m, const float* __restrict__ pbuf,
                                            const int* __restrict__ row_off, const int* __restrict__ csr,
                                            float* __restrict__ out, int N) {
    int t = blockIdx.x * blockDim.x + threadIdx.x;
    int node = t >> 6;
    int d = t & 63;
    if (node >= N) return;
    int beg = row_off[node], end = row_off[node + 1];
    float a0 = -INFINITY, a1 = -INFINITY, a2 = -INFINITY, a3 = -INFINITY;
    int j = beg;
    for (; j + 3 < end; j += 4) {
        int s0 = csr[j], s1 = csr[j + 1], s2 = csr[j + 2], s3 = csr[j + 3];
        a0 = fmaxf(a0, -m[s0 * 64 + d]);
        a1 = fmaxf(a1, -m[s1 * 64 + d]);
        a2 = fmaxf(a2, -m[s2 * 64 + d]);
        a3 = fmaxf(a3, -m[s3 * 64 + d]);
    }
    for (; j < end; ++j) {
        int s = csr[j];
        a0 = fmaxf(a0, -m[s * 64 + d]);
    }
    float r = 0.f;
    if (end > beg) r = fmaxf(pbuf[node * 64 + d] + fmaxf(fmaxf(a0, a1), fmaxf(a2, a3)), 0.f);
    out[node * 64 + d] = r;
}

// ---------------- graph mean pooling (segmented: gid is sorted) ----------------

__global__ __launch_bounds__(256) void k_pool(const float* __restrict__ h, const int* __restrict__ gid,
                                              float* __restrict__ out, float* __restrict__ gcnt, int N) {
    const int CHUNK = 128;
    int wave = blockIdx.x * 4 + (threadIdx.x >> 6);
    int lane = threadIdx.x & 63;
    int beg = wave * CHUNK;
    if (beg >= N) return;
    int end = beg + CHUNK < N ? beg + CHUNK : N;
    int gcur = gid[beg];
    float acc = 0.f;
    int cnt = 0;
    for (int n = beg; n < end; ++n) {
        int g = gid[n];
        float v = h[n * 64 + lane];
        if (g != gcur) {
            atomicAdd(&out[gcur * 64 + lane], acc);
            if (lane == 0) atomicAdd(&gcnt[gcur], (float)cnt);
            gcur = g; acc = 0.f; cnt = 0;
        }
        acc += v;
        ++cnt;
    }
    atomicAdd(&out[gcur * 64 + lane], acc);
    if (lane == 0) atomicAdd(&gcnt[gcur], (float)cnt);
}

__global__ __launch_bounds__(256) void k_div(float* __restrict__ out, const float* __restrict__ gcnt, int total) {
    int i = blockIdx.x * blockDim.x + threadIdx.x;
    if (i < total) out[i] /= fmaxf(gcnt[i >> 6], 1.f);
}

// ---------------- launcher ----------------

extern "C" void kernel_launch(void* const* d_in, const int* in_sizes, int n_in,
                              void* d_out, int out_size, void* d_ws, size_t ws_size,
                              hipStream_t stream) {
    const float* feat = (const float*)d_in[0];
    const int* src = (const int*)d_in[1];
    const int* dst = (const int*)d_in[2];
    const int* gid = (const int*)d_in[3];
    const float* W1 = (const float*)d_in[4];  const float* b1 = (const float*)d_in[5];
    const float* W2 = (const float*)d_in[6];  const float* b2 = (const float*)d_in[7];
    const float* W3 = (const float*)d_in[8];  const float* b3 = (const float*)d_in[9];
    const float* Wt1 = (const float*)d_in[10]; const float* bt1 = (const float*)d_in[11];
    const float* Wp1 = (const float*)d_in[12]; const float* bp1 = (const float*)d_in[13];
    const float* Wt2 = (const float*)d_in[14]; const float* bt2 = (const float*)d_in[15];
    const float* Wp2 = (const float*)d_in[16]; const float* bp2 = (const float*)d_in[17];
    float* out = (float*)d_out;

    const int N = in_sizes[0] / 16;
    const int E = in_sizes[1];
    const int G = out_size / 64;

    char* p = (char*)d_ws;
    auto alloc = [&](size_t nbytes) {
        void* r = (void*)p;
        p += (nbytes + 255) & ~(size_t)255;
        return r;
    };
    int* cnt      = (int*)alloc((size_t)N * 4);
    int* row_off  = (int*)alloc((size_t)(N + 1) * 4);
    int* cursor   = (int*)alloc((size_t)N * 4);
    int* csr      = (int*)alloc((size_t)E * 4);
    int* bsum     = (int*)alloc(512 * 4);
    float* dinv   = (float*)alloc((size_t)N * 4);
    float* bufA   = (float*)alloc((size_t)N * 64 * 4);
    float* bufB   = (float*)alloc((size_t)N * 64 * 4);
    float* bufC   = (float*)alloc((size_t)N * 64 * 4);
    float* bufD   = (float*)alloc((size_t)N * 64 * 4);
    float* gcnt   = (float*)alloc((size_t)G * 4);

    hipMemsetAsync(cnt, 0, (size_t)N * 4, stream);
    hipMemsetAsync(gcnt, 0, (size_t)G * 4, stream);
    hipMemsetAsync(d_out, 0, (size_t)out_size * 4, stream);

    const int B = (N + 255) / 256;
    const int ebk = (E + 255) / 256;
    const int nb64 = (N * 64 + 255) / 256;
    const int nb16 = (N * 16 + 255) / 256;
    const int npool = ((N + 127) / 128 + 3) / 4;

    const int g_cheb64 = 768;   // 48KB LDS -> 3 blocks/CU
    const int g_cheb16 = 1024;  // 12KB LDS
    const int g_e1     = 1024;  // 32KB LDS -> 4 blocks/CU at this grid

    k_hist<<<ebk, 256, 0, stream>>>(dst, cnt, E);
    k_scanA<<<B, 256, 0, stream>>>(cnt, bsum, N);
    k_scanB<<<1, 512, 0, stream>>>(bsum, B);
    k_scanC<<<B, 256, 0, stream>>>(cnt, bsum, row_off, cursor, dinv, N, E);
    k_scatter<<<ebk, 256, 0, stream>>>(src, dst, cursor, csr, E);

    // ---- Cheb layer 1 (IN=16) : X1 = -aggr(X0); X2 = -2*aggr(X1) - X0
    k_aggr<16><<<nb16, 256, 0, stream>>>(feat, nullptr, dinv, row_off, csr, bufA, -1.f, 0.f, N);
    k_aggr<16><<<nb16, 256, 0, stream>>>(bufA, feat, dinv, row_off, csr, bufB, -2.f, -1.f, N);
    k_cheb_mm<16><<<g_cheb16, 256, 0, stream>>>(feat, bufA, bufB, W1, b1, bufC, N);

    // ---- EdgeConv 1
    k_e1<<<g_e1, 256, 0, stream>>>(bufC, Wt1, Wp1, bt1, bp1, bufA, bufB, N);
    k_e2<<<nb64, 256, 0, stream>>>(bufA, bufB, row_off, csr, bufD, N);

    // ---- Cheb layer 2
    k_aggr<64><<<nb64, 256, 0, stream>>>(bufD, nullptr, dinv, row_off, csr, bufA, -1.f, 0.f, N);
    k_aggr<64><<<nb64, 256, 0, stream>>>(bufA, bufD, dinv, row_off, csr, bufB, -2.f, -1.f, N);
    k_cheb_mm<64><<<g_cheb64, 256, 0, stream>>>(bufD, bufA, bufB, W2, b2, bufC, N);

    // ---- EdgeConv 2
    k_e1<<<g_e1, 256, 0, stream>>>(bufC, Wt2, Wp2, bt2, bp2, bufA, bufB, N);
    k_e2<<<nb64, 256, 0, stream>>>(bufA, bufB, row_off, csr, bufD, N);

    // ---- Cheb layer 3
    k_aggr<64><<<nb64, 256, 0, stream>>>(bufD, nullptr, dinv, row_off, csr, bufA, -1.f, 0.f, N);
    k_aggr<64><<<nb64, 256, 0, stream>>>(bufA, bufD, dinv, row_off, csr, bufB, -2.f, -1.f, N);
    k_cheb_mm<64><<<g_cheb64, 256, 0, stream>>>(bufD, bufA, bufB, W3, b3, bufC, N);

    // ---- per-graph mean pooling
    k_pool<<<npool, 256, 0, stream>>>(bufC, gid, out, gcnt, N);
    k_div<<<(out_size + 255) / 256, 256, 0, stream>>>(out, gcnt, out_size);
}

// Round 5
// 1198.981 us; speedup vs baseline: 4.6219x; 4.6219x over previous
//
#include <hip/hip_runtime.h>
#include <hip/hip_bf16.h>
#include <math.h>

// ---------------- CSR build ----------------

__global__ __launch_bounds__(256) void k_hist(const int* __restrict__ dst, int* __restrict__ cnt, int E) {
    int i = blockIdx.x * blockDim.x + threadIdx.x;
    if (i < E) atomicAdd(&cnt[dst[i]], 1);
}

__global__ __launch_bounds__(256) void k_scanA(const int* __restrict__ cnt, int* __restrict__ bsum, int N) {
    __shared__ int s[256];
    int t = threadIdx.x;
    int i = blockIdx.x * 256 + t;
    s[t] = (i < N) ? cnt[i] : 0;
    __syncthreads();
    for (int off = 128; off > 0; off >>= 1) {
        if (t < off) s[t] += s[t + off];
        __syncthreads();
    }
    if (t == 0) bsum[blockIdx.x] = s[0];
}

__global__ __launch_bounds__(512) void k_scanB(int* __restrict__ bsum, int B) {
    __shared__ int s[512];
    int t = threadIdx.x;
    int v = (t < B) ? bsum[t] : 0;
    s[t] = v;
    __syncthreads();
    for (int off = 1; off < 512; off <<= 1) {
        int x = (t >= off) ? s[t - off] : 0;
        __syncthreads();
        s[t] += x;
        __syncthreads();
    }
    if (t < B) bsum[t] = s[t] - v;   // exclusive
}

__global__ __launch_bounds__(256) void k_scanC(const int* __restrict__ cnt, const int* __restrict__ bsum,
                                               int* __restrict__ row_off, int* __restrict__ cursor,
                                               float* __restrict__ dinv, int N, int E) {
    __shared__ int s[256];
    int t = threadIdx.x;
    int i = blockIdx.x * 256 + t;
    int v = (i < N) ? cnt[i] : 0;
    s[t] = v;
    __syncthreads();
    for (int off = 1; off < 256; off <<= 1) {
        int x = (t >= off) ? s[t - off] : 0;
        __syncthreads();
        s[t] += x;
        __syncthreads();
    }
    if (i < N) {
        int excl = bsum[blockIdx.x] + s[t] - v;
        row_off[i] = excl;
        cursor[i]  = excl;
        dinv[i]    = rsqrtf((float)(v > 1 ? v : 1));
    }
    if (i == 0) row_off[N] = E;
}

__global__ __launch_bounds__(256) void k_scatter(const int* __restrict__ src, const int* __restrict__ dst,
                                                 int* __restrict__ cursor, int* __restrict__ csr, int E) {
    int i = blockIdx.x * blockDim.x + threadIdx.x;
    if (i < E) {
        int d = dst[i];
        int pos = atomicAdd(&cursor[d], 1);
        csr[pos] = src[i];
    }
}

// ---------------- Chebyshev aggregation: out = alpha * (dinv[n] * sum_j X[j]*dinv[j]) + beta * Z[n] ----------------

template <int D>
__global__ __launch_bounds__(256) void k_aggr(const float* __restrict__ X, const float* __restrict__ Z,
                                              const float* __restrict__ dinv,
                                              const int* __restrict__ row_off, const int* __restrict__ csr,
                                              float* __restrict__ out, float alpha, float beta, int N) {
    int t = blockIdx.x * blockDim.x + threadIdx.x;
    int node = t / D;
    int d = t % D;
    if (node >= N) return;
    int beg = row_off[node], end = row_off[node + 1];
    float a0 = 0.f, a1 = 0.f, a2 = 0.f, a3 = 0.f;
    int j = beg;
    for (; j + 3 < end; j += 4) {
        int s0 = csr[j], s1 = csr[j + 1], s2 = csr[j + 2], s3 = csr[j + 3];
        a0 += X[s0 * D + d] * dinv[s0];
        a1 += X[s1 * D + d] * dinv[s1];
        a2 += X[s2 * D + d] * dinv[s2];
        a3 += X[s3 * D + d] * dinv[s3];
    }
    for (; j < end; ++j) {
        int s = csr[j];
        a0 += X[s * D + d] * dinv[s];
    }
    float acc = (a0 + a1) + (a2 + a3);
    float v = alpha * dinv[node] * acc;
    if (Z) v += beta * Z[node * D + d];
    out[node * D + d] = v;
}

// ---------------- Cheb matmul, LDS-tiled GEMM ----------------
// out[64-node tile] = relu(b + X0@W0 + X1@W1 + X2@W2). Per block: W (3*KDIM*64) staged
// once; each of 3 K-chunks stages X transposed (Xs[k][n], stride 65 -> conflict-free).
// Thread = 2 nodes x 8 cols -> 16 independent acc chains, no shfl, no spill.

template <int KDIM>
__global__ __launch_bounds__(256) void k_cheb_t(const float* __restrict__ X0, const float* __restrict__ X1,
                                                const float* __restrict__ X2, const float* __restrict__ W,
                                                const float* __restrict__ b, float* __restrict__ out, int N) {
    __shared__ float Ws[3 * KDIM * 64];
    __shared__ float Xs[KDIM * 65];
    int t = threadIdx.x;
    for (int idx = t; idx < 3 * KDIM * 64; idx += 256) Ws[idx] = W[idx];

    int nbase = blockIdx.x * 64;
    int ln0 = t & 31;            // local node 0
    int ln1 = 32 + ln0;          // local node 1
    int c0  = (t >> 5) * 8;      // 8 output cols

    // staging mapping: node = t&63, k-span = (t>>6)*(KDIM/4)
    int sn  = t & 63;
    int sk0 = (t >> 6) * (KDIM / 4);
    int gn  = nbase + sn; if (gn >= N) gn = N - 1;

    float a0[8], a1[8];
#pragma unroll
    for (int i = 0; i < 8; ++i) { a0[i] = 0.f; a1[i] = 0.f; }

#pragma unroll
    for (int a = 0; a < 3; ++a) {
        const float* X = (a == 0) ? X0 : ((a == 1) ? X1 : X2);
        __syncthreads();   // Xs free (and Ws ready on first iter)
#pragma unroll
        for (int i = 0; i < KDIM / 16; ++i) {
            float4 v = *(const float4*)&X[(size_t)gn * KDIM + sk0 + 4 * i];
            Xs[(sk0 + 4 * i + 0) * 65 + sn] = v.x;
            Xs[(sk0 + 4 * i + 1) * 65 + sn] = v.y;
            Xs[(sk0 + 4 * i + 2) * 65 + sn] = v.z;
            Xs[(sk0 + 4 * i + 3) * 65 + sn] = v.w;
        }
        __syncthreads();
#pragma unroll 16
        for (int k = 0; k < KDIM; ++k) {
            float x0 = Xs[k * 65 + ln0];
            float x1 = Xs[k * 65 + ln1];
            const float4* wr = (const float4*)&Ws[(a * KDIM + k) * 64 + c0];
            float4 wA = wr[0];
            float4 wB = wr[1];
            a0[0] += x0 * wA.x; a0[1] += x0 * wA.y; a0[2] += x0 * wA.z; a0[3] += x0 * wA.w;
            a0[4] += x0 * wB.x; a0[5] += x0 * wB.y; a0[6] += x0 * wB.z; a0[7] += x0 * wB.w;
            a1[0] += x1 * wA.x; a1[1] += x1 * wA.y; a1[2] += x1 * wA.z; a1[3] += x1 * wA.w;
            a1[4] += x1 * wB.x; a1[5] += x1 * wB.y; a1[6] += x1 * wB.z; a1[7] += x1 * wB.w;
        }
    }

    float4 bA = *(const float4*)&b[c0];
    float4 bB = *(const float4*)&b[c0 + 4];
    int n0 = nbase + ln0, n1 = nbase + ln1;
    if (n0 < N) {
        float4 r0 = { fmaxf(a0[0] + bA.x, 0.f), fmaxf(a0[1] + bA.y, 0.f), fmaxf(a0[2] + bA.z, 0.f), fmaxf(a0[3] + bA.w, 0.f) };
        float4 r1 = { fmaxf(a0[4] + bB.x, 0.f), fmaxf(a0[5] + bB.y, 0.f), fmaxf(a0[6] + bB.z, 0.f), fmaxf(a0[7] + bB.w, 0.f) };
        *(float4*)&out[(size_t)n0 * 64 + c0] = r0;
        *(float4*)&out[(size_t)n0 * 64 + c0 + 4] = r1;
    }
    if (n1 < N) {
        float4 r0 = { fmaxf(a1[0] + bA.x, 0.f), fmaxf(a1[1] + bA.y, 0.f), fmaxf(a1[2] + bA.z, 0.f), fmaxf(a1[3] + bA.w, 0.f) };
        float4 r1 = { fmaxf(a1[4] + bB.x, 0.f), fmaxf(a1[5] + bB.y, 0.f), fmaxf(a1[6] + bB.z, 0.f), fmaxf(a1[7] + bB.w, 0.f) };
        *(float4*)&out[(size_t)n1 * 64 + c0] = r0;
        *(float4*)&out[(size_t)n1 * 64 + c0 + 4] = r1;
    }
}

// ---------------- EdgeConv stage 1 as tiled GEMM: [m|p] = X @ [Wt | Wt+Wp] ----------------
// W LDS = 64x128 concat; thread = 2 nodes x 16 cols (one band lies fully in m or p).

__global__ __launch_bounds__(256) void k_e1_t(const float* __restrict__ X, const float* __restrict__ Wt,
                                              const float* __restrict__ Wp, const float* __restrict__ bt,
                                              const float* __restrict__ bp, float* __restrict__ m,
                                              float* __restrict__ pbuf, int N) {
    __shared__ float Wl[64 * 128];
    __shared__ float Xs[64 * 65];
    int t = threadIdx.x;
    for (int idx = t; idx < 64 * 64; idx += 256) {
        int k = idx >> 6, c = idx & 63;
        float wt = Wt[idx];
        Wl[k * 128 + c] = wt;
        Wl[k * 128 + 64 + c] = wt + Wp[idx];
    }

    int nbase = blockIdx.x * 64;
    int ln0 = t & 31, ln1 = 32 + ln0;
    int c0 = (t >> 5) * 16;      // 16 cols in [0,128)

    int sn = t & 63;
    int sk0 = (t >> 6) * 16;
    int gn = nbase + sn; if (gn >= N) gn = N - 1;
#pragma unroll
    for (int i = 0; i < 4; ++i) {
        float4 v = *(const float4*)&X[(size_t)gn * 64 + sk0 + 4 * i];
        Xs[(sk0 + 4 * i + 0) * 65 + sn] = v.x;
        Xs[(sk0 + 4 * i + 1) * 65 + sn] = v.y;
        Xs[(sk0 + 4 * i + 2) * 65 + sn] = v.z;
        Xs[(sk0 + 4 * i + 3) * 65 + sn] = v.w;
    }
    __syncthreads();

    float a0[16], a1[16];
#pragma unroll
    for (int i = 0; i < 16; ++i) { a0[i] = 0.f; a1[i] = 0.f; }

#pragma unroll 8
    for (int k = 0; k < 64; ++k) {
        float x0 = Xs[k * 65 + ln0];
        float x1 = Xs[k * 65 + ln1];
        const float4* wr = (const float4*)&Wl[k * 128 + c0];
#pragma unroll
        for (int q = 0; q < 4; ++q) {
            float4 w = wr[q];
            a0[4 * q + 0] += x0 * w.x; a0[4 * q + 1] += x0 * w.y; a0[4 * q + 2] += x0 * w.z; a0[4 * q + 3] += x0 * w.w;
            a1[4 * q + 0] += x1 * w.x; a1[4 * q + 1] += x1 * w.y; a1[4 * q + 2] += x1 * w.z; a1[4 * q + 3] += x1 * w.w;
        }
    }

    int n0 = nbase + ln0, n1 = nbase + ln1;
    if (c0 < 64) {               // this band -> m (no bias)
        if (n0 < N) {
#pragma unroll
            for (int q = 0; q < 4; ++q) {
                float4 r = { a0[4 * q], a0[4 * q + 1], a0[4 * q + 2], a0[4 * q + 3] };
                *(float4*)&m[(size_t)n0 * 64 + c0 + 4 * q] = r;
            }
        }
        if (n1 < N) {
#pragma unroll
            for (int q = 0; q < 4; ++q) {
                float4 r = { a1[4 * q], a1[4 * q + 1], a1[4 * q + 2], a1[4 * q + 3] };
                *(float4*)&m[(size_t)n1 * 64 + c0 + 4 * q] = r;
            }
        }
    } else {                     // this band -> pbuf (+ bias)
        int cc = c0 - 64;
        float bb[16];
#pragma unroll
        for (int i = 0; i < 16; ++i) bb[i] = bt[cc + i] + bp[cc + i];
        if (n0 < N) {
#pragma unroll
            for (int q = 0; q < 4; ++q) {
                float4 r = { a0[4 * q] + bb[4 * q], a0[4 * q + 1] + bb[4 * q + 1], a0[4 * q + 2] + bb[4 * q + 2], a0[4 * q + 3] + bb[4 * q + 3] };
                *(float4*)&pbuf[(size_t)n0 * 64 + cc + 4 * q] = r;
            }
        }
        if (n1 < N) {
#pragma unroll
            for (int q = 0; q < 4; ++q) {
                float4 r = { a1[4 * q] + bb[4 * q], a1[4 * q + 1] + bb[4 * q + 1], a1[4 * q + 2] + bb[4 * q + 2], a1[4 * q + 3] + bb[4 * q + 3] };
                *(float4*)&pbuf[(size_t)n1 * 64 + cc + 4 * q] = r;
            }
        }
    }
}

// ---------------- EdgeConv stage 2: out = relu(p[n] + max_j(-m[src_j])), 0 if no in-edges ----------------

__global__ __launch_bounds__(256) void k_e2(const float* __restrict__ m, const float* __restrict__ pbuf,
                                            const int* __restrict__ row_off, const int* __restrict__ csr,
                                            float* __restrict__ out, int N) {
    int t = blockIdx.x * blockDim.x + threadIdx.x;
    int node = t >> 6;
    int d = t & 63;
    if (node >= N) return;
    int beg = row_off[node], end = row_off[node + 1];
    float a0 = -INFINITY, a1 = -INFINITY, a2 = -INFINITY, a3 = -INFINITY;
    int j = beg;
    for (; j + 3 < end; j += 4) {
        int s0 = csr[j], s1 = csr[j + 1], s2 = csr[j + 2], s3 = csr[j + 3];
        a0 = fmaxf(a0, -m[s0 * 64 + d]);
        a1 = fmaxf(a1, -m[s1 * 64 + d]);
        a2 = fmaxf(a2, -m[s2 * 64 + d]);
        a3 = fmaxf(a3, -m[s3 * 64 + d]);
    }
    for (; j < end; ++j) {
        int s = csr[j];
        a0 = fmaxf(a0, -m[s * 64 + d]);
    }
    float r = 0.f;
    if (end > beg) r = fmaxf(pbuf[node * 64 + d] + fmaxf(fmaxf(a0, a1), fmaxf(a2, a3)), 0.f);
    out[node * 64 + d] = r;
}

// ---------------- graph mean pooling (segmented: gid is sorted) ----------------

__global__ __launch_bounds__(256) void k_pool(const float* __restrict__ h, const int* __restrict__ gid,
                                              float* __restrict__ out, float* __restrict__ gcnt, int N) {
    const int CHUNK = 128;
    int wave = blockIdx.x * 4 + (threadIdx.x >> 6);
    int lane = threadIdx.x & 63;
    int beg = wave * CHUNK;
    if (beg >= N) return;
    int end = beg + CHUNK < N ? beg + CHUNK : N;
    int gcur = gid[beg];
    float acc = 0.f;
    int cnt = 0;
    for (int n = beg; n < end; ++n) {
        int g = gid[n];
        float v = h[n * 64 + lane];
        if (g != gcur) {
            atomicAdd(&out[gcur * 64 + lane], acc);
            if (lane == 0) atomicAdd(&gcnt[gcur], (float)cnt);
            gcur = g; acc = 0.f; cnt = 0;
        }
        acc += v;
        ++cnt;
    }
    atomicAdd(&out[gcur * 64 + lane], acc);
    if (lane == 0) atomicAdd(&gcnt[gcur], (float)cnt);
}

__global__ __launch_bounds__(256) void k_div(float* __restrict__ out, const float* __restrict__ gcnt, int total) {
    int i = blockIdx.x * blockDim.x + threadIdx.x;
    if (i < total) out[i] /= fmaxf(gcnt[i >> 6], 1.f);
}

// ---------------- launcher ----------------

extern "C" void kernel_launch(void* const* d_in, const int* in_sizes, int n_in,
                              void* d_out, int out_size, void* d_ws, size_t ws_size,
                              hipStream_t stream) {
    const float* feat = (const float*)d_in[0];
    const int* src = (const int*)d_in[1];
    const int* dst = (const int*)d_in[2];
    const int* gid = (const int*)d_in[3];
    const float* W1 = (const float*)d_in[4];  const float* b1 = (const float*)d_in[5];
    const float* W2 = (const float*)d_in[6];  const float* b2 = (const float*)d_in[7];
    const float* W3 = (const float*)d_in[8];  const float* b3 = (const float*)d_in[9];
    const float* Wt1 = (const float*)d_in[10]; const float* bt1 = (const float*)d_in[11];
    const float* Wp1 = (const float*)d_in[12]; const float* bp1 = (const float*)d_in[13];
    const float* Wt2 = (const float*)d_in[14]; const float* bt2 = (const float*)d_in[15];
    const float* Wp2 = (const float*)d_in[16]; const float* bp2 = (const float*)d_in[17];
    float* out = (float*)d_out;

    const int N = in_sizes[0] / 16;
    const int E = in_sizes[1];
    const int G = out_size / 64;

    char* p = (char*)d_ws;
    auto alloc = [&](size_t nbytes) {
        void* r = (void*)p;
        p += (nbytes + 255) & ~(size_t)255;
        return r;
    };
    int* cnt      = (int*)alloc((size_t)N * 4);
    int* row_off  = (int*)alloc((size_t)(N + 1) * 4);
    int* cursor   = (int*)alloc((size_t)N * 4);
    int* csr      = (int*)alloc((size_t)E * 4);
    int* bsum     = (int*)alloc(512 * 4);
    float* dinv   = (float*)alloc((size_t)N * 4);
    float* bufA   = (float*)alloc((size_t)N * 64 * 4);
    float* bufB   = (float*)alloc((size_t)N * 64 * 4);
    float* bufC   = (float*)alloc((size_t)N * 64 * 4);
    float* bufD   = (float*)alloc((size_t)N * 64 * 4);
    float* gcnt   = (float*)alloc((size_t)G * 4);

    hipMemsetAsync(cnt, 0, (size_t)N * 4, stream);
    hipMemsetAsync(gcnt, 0, (size_t)G * 4, stream);
    hipMemsetAsync(d_out, 0, (size_t)out_size * 4, stream);

    const int B = (N + 255) / 256;
    const int ebk = (E + 255) / 256;
    const int nb64 = (N * 64 + 255) / 256;
    const int nb16 = (N * 16 + 255) / 256;
    const int npool = ((N + 127) / 128 + 3) / 4;
    const int nbt = (N + 63) / 64;     // tiled GEMM blocks

    k_hist<<<ebk, 256, 0, stream>>>(dst, cnt, E);
    k_scanA<<<B, 256, 0, stream>>>(cnt, bsum, N);
    k_scanB<<<1, 512, 0, stream>>>(bsum, B);
    k_scanC<<<B, 256, 0, stream>>>(cnt, bsum, row_off, cursor, dinv, N, E);
    k_scatter<<<ebk, 256, 0, stream>>>(src, dst, cursor, csr, E);

    // ---- Cheb layer 1 (IN=16) : X1 = -aggr(X0); X2 = -2*aggr(X1) - X0
    k_aggr<16><<<nb16, 256, 0, stream>>>(feat, nullptr, dinv, row_off, csr, bufA, -1.f, 0.f, N);
    k_aggr<16><<<nb16, 256, 0, stream>>>(bufA, feat, dinv, row_off, csr, bufB, -2.f, -1.f, N);
    k_cheb_t<16><<<nbt, 256, 0, stream>>>(feat, bufA, bufB, W1, b1, bufC, N);

    // ---- EdgeConv 1
    k_e1_t<<<nbt, 256, 0, stream>>>(bufC, Wt1, Wp1, bt1, bp1, bufA, bufB, N);
    k_e2<<<nb64, 256, 0, stream>>>(bufA, bufB, row_off, csr, bufD, N);

    // ---- Cheb layer 2
    k_aggr<64><<<nb64, 256, 0, stream>>>(bufD, nullptr, dinv, row_off, csr, bufA, -1.f, 0.f, N);
    k_aggr<64><<<nb64, 256, 0, stream>>>(bufA, bufD, dinv, row_off, csr, bufB, -2.f, -1.f, N);
    k_cheb_t<64><<<nbt, 256, 0, stream>>>(bufD, bufA, bufB, W2, b2, bufC, N);

    // ---- EdgeConv 2
    k_e1_t<<<nbt, 256, 0, stream>>>(bufC, Wt2, Wp2, bt2, bp2, bufA, bufB, N);
    k_e2<<<nb64, 256, 0, stream>>>(bufA, bufB, row_off, csr, bufD, N);

    // ---- Cheb layer 3
    k_aggr<64><<<nb64, 256, 0, stream>>>(bufD, nullptr, dinv, row_off, csr, bufA, -1.f, 0.f, N);
    k_aggr<64><<<nb64, 256, 0, stream>>>(bufA, bufD, dinv, row_off, csr, bufB, -2.f, -1.f, N);
    k_cheb_t<64><<<nbt, 256, 0, stream>>>(bufD, bufA, bufB, W3, b3, bufC, N);

    // ---- per-graph mean pooling
    k_pool<<<npool, 256, 0, stream>>>(bufC, gid, out, gcnt, N);
    k_div<<<(out_size + 255) / 256, 256, 0, stream>>>(out, gcnt, out_size);
}

// Round 6
// 1037.731 us; speedup vs baseline: 5.3400x; 1.1554x over previous
//
#include <hip/hip_runtime.h>
#include <hip/hip_bf16.h>
#include <math.h>

// ---------------- CSR build ----------------

__global__ __launch_bounds__(256) void k_hist(const int* __restrict__ dst, int* __restrict__ cnt, int E) {
    int i = blockIdx.x * blockDim.x + threadIdx.x;
    if (i < E) atomicAdd(&cnt[dst[i]], 1);
}

__global__ __launch_bounds__(256) void k_scanA(const int* __restrict__ cnt, int* __restrict__ bsum, int N) {
    __shared__ int s[256];
    int t = threadIdx.x;
    int i = blockIdx.x * 256 + t;
    s[t] = (i < N) ? cnt[i] : 0;
    __syncthreads();
    for (int off = 128; off > 0; off >>= 1) {
        if (t < off) s[t] += s[t + off];
        __syncthreads();
    }
    if (t == 0) bsum[blockIdx.x] = s[0];
}

__global__ __launch_bounds__(512) void k_scanB(int* __restrict__ bsum, int B) {
    __shared__ int s[512];
    int t = threadIdx.x;
    int v = (t < B) ? bsum[t] : 0;
    s[t] = v;
    __syncthreads();
    for (int off = 1; off < 512; off <<= 1) {
        int x = (t >= off) ? s[t - off] : 0;
        __syncthreads();
        s[t] += x;
        __syncthreads();
    }
    if (t < B) bsum[t] = s[t] - v;   // exclusive
}

__global__ __launch_bounds__(256) void k_scanC(const int* __restrict__ cnt, const int* __restrict__ bsum,
                                               int* __restrict__ row_off, int* __restrict__ cursor,
                                               float* __restrict__ dinv, int N, int E) {
    __shared__ int s[256];
    int t = threadIdx.x;
    int i = blockIdx.x * 256 + t;
    int v = (i < N) ? cnt[i] : 0;
    s[t] = v;
    __syncthreads();
    for (int off = 1; off < 256; off <<= 1) {
        int x = (t >= off) ? s[t - off] : 0;
        __syncthreads();
        s[t] += x;
        __syncthreads();
    }
    if (i < N) {
        int excl = bsum[blockIdx.x] + s[t] - v;
        row_off[i] = excl;
        cursor[i]  = excl;
        dinv[i]    = rsqrtf((float)(v > 1 ? v : 1));
    }
    if (i == 0) row_off[N] = E;
}

__global__ __launch_bounds__(256) void k_scatter(const int* __restrict__ src, const int* __restrict__ dst,
                                                 int* __restrict__ cursor, int* __restrict__ csr, int E) {
    int i = blockIdx.x * blockDim.x + threadIdx.x;
    if (i < E) {
        int d = dst[i];
        int pos = atomicAdd(&cursor[d], 1);
        csr[pos] = src[i];
    }
}

// ---------------- Chebyshev aggregation: out = alpha * (dinv[n] * sum_j X[j]*dinv[j]) + beta * Z[n] ----------------

template <int D>
__global__ __launch_bounds__(256) void k_aggr(const float* __restrict__ X, const float* __restrict__ Z,
                                              const float* __restrict__ dinv,
                                              const int* __restrict__ row_off, const int* __restrict__ csr,
                                              float* __restrict__ out, float alpha, float beta, int N) {
    int t = blockIdx.x * blockDim.x + threadIdx.x;
    int node = t / D;
    int d = t % D;
    if (node >= N) return;
    int beg = row_off[node], end = row_off[node + 1];
    float a0 = 0.f, a1 = 0.f, a2 = 0.f, a3 = 0.f;
    int j = beg;
    for (; j + 3 < end; j += 4) {
        int s0 = csr[j], s1 = csr[j + 1], s2 = csr[j + 2], s3 = csr[j + 3];
        a0 += X[s0 * D + d] * dinv[s0];
        a1 += X[s1 * D + d] * dinv[s1];
        a2 += X[s2 * D + d] * dinv[s2];
        a3 += X[s3 * D + d] * dinv[s3];
    }
    for (; j < end; ++j) {
        int s = csr[j];
        a0 += X[s * D + d] * dinv[s];
    }
    float acc = (a0 + a1) + (a2 + a3);
    float v = alpha * dinv[node] * acc;
    if (Z) v += beta * Z[node * D + d];
    out[node * D + d] = v;
}

// ---------------- Cheb matmul, LDS-tiled GEMM ----------------
// out[64-node tile] = relu(b + X0@W0 + X1@W1 + X2@W2). Unroll policy is deliberate:
// chunk loop FORCED rolled (unroll 1) and k-loop capped at 4 — full unrolling made the
// compiler pipeline ~96 float4 LDS reads -> 256 VGPRs -> scratch spill (R5: 386MB traffic).

template <int KDIM>
__global__ __launch_bounds__(256) void k_cheb_t(const float* __restrict__ X0, const float* __restrict__ X1,
                                                const float* __restrict__ X2, const float* __restrict__ W,
                                                const float* __restrict__ b, float* __restrict__ out, int N) {
    __shared__ float Ws[3 * KDIM * 64];
    __shared__ float Xs[KDIM * 65];
    int t = threadIdx.x;
    for (int idx = t; idx < 3 * KDIM * 64; idx += 256) Ws[idx] = W[idx];

    int nbase = blockIdx.x * 64;
    int ln0 = t & 31;            // local node 0
    int ln1 = 32 + ln0;          // local node 1
    int c0  = (t >> 5) * 8;      // 8 output cols

    int sn  = t & 63;
    int sk0 = (t >> 6) * (KDIM / 4);
    int gn  = nbase + sn; if (gn >= N) gn = N - 1;

    float a0[8], a1[8];
#pragma unroll
    for (int i = 0; i < 8; ++i) { a0[i] = 0.f; a1[i] = 0.f; }

    const float* Xp[3] = { X0, X1, X2 };
#pragma unroll 1
    for (int a = 0; a < 3; ++a) {
        const float* X = Xp[a];
        __syncthreads();   // Xs free (and Ws ready on first iter)
#pragma unroll
        for (int i = 0; i < KDIM / 16; ++i) {
            float4 v = *(const float4*)&X[(size_t)gn * KDIM + sk0 + 4 * i];
            Xs[(sk0 + 4 * i + 0) * 65 + sn] = v.x;
            Xs[(sk0 + 4 * i + 1) * 65 + sn] = v.y;
            Xs[(sk0 + 4 * i + 2) * 65 + sn] = v.z;
            Xs[(sk0 + 4 * i + 3) * 65 + sn] = v.w;
        }
        __syncthreads();
#pragma unroll 4
        for (int k = 0; k < KDIM; ++k) {
            float x0 = Xs[k * 65 + ln0];
            float x1 = Xs[k * 65 + ln1];
            const float4* wr = (const float4*)&Ws[(a * KDIM + k) * 64 + c0];
            float4 wA = wr[0];
            float4 wB = wr[1];
            a0[0] += x0 * wA.x; a0[1] += x0 * wA.y; a0[2] += x0 * wA.z; a0[3] += x0 * wA.w;
            a0[4] += x0 * wB.x; a0[5] += x0 * wB.y; a0[6] += x0 * wB.z; a0[7] += x0 * wB.w;
            a1[0] += x1 * wA.x; a1[1] += x1 * wA.y; a1[2] += x1 * wA.z; a1[3] += x1 * wA.w;
            a1[4] += x1 * wB.x; a1[5] += x1 * wB.y; a1[6] += x1 * wB.z; a1[7] += x1 * wB.w;
        }
    }

    float4 bA = *(const float4*)&b[c0];
    float4 bB = *(const float4*)&b[c0 + 4];
    int n0 = nbase + ln0, n1 = nbase + ln1;
    if (n0 < N) {
        float4 r0 = { fmaxf(a0[0] + bA.x, 0.f), fmaxf(a0[1] + bA.y, 0.f), fmaxf(a0[2] + bA.z, 0.f), fmaxf(a0[3] + bA.w, 0.f) };
        float4 r1 = { fmaxf(a0[4] + bB.x, 0.f), fmaxf(a0[5] + bB.y, 0.f), fmaxf(a0[6] + bB.z, 0.f), fmaxf(a0[7] + bB.w, 0.f) };
        *(float4*)&out[(size_t)n0 * 64 + c0] = r0;
        *(float4*)&out[(size_t)n0 * 64 + c0 + 4] = r1;
    }
    if (n1 < N) {
        float4 r0 = { fmaxf(a1[0] + bA.x, 0.f), fmaxf(a1[1] + bA.y, 0.f), fmaxf(a1[2] + bA.z, 0.f), fmaxf(a1[3] + bA.w, 0.f) };
        float4 r1 = { fmaxf(a1[4] + bB.x, 0.f), fmaxf(a1[5] + bB.y, 0.f), fmaxf(a1[6] + bB.z, 0.f), fmaxf(a1[7] + bB.w, 0.f) };
        *(float4*)&out[(size_t)n1 * 64 + c0] = r0;
        *(float4*)&out[(size_t)n1 * 64 + c0 + 4] = r1;
    }
}

// ---------------- EdgeConv stage 1 as tiled GEMM: [m|p] = X @ [Wt | Wt+Wp] ----------------
// k-loop unroll capped at 2 (32 acc chains x 2 = 64 FMA of ILP; full unroll risks spill).

__global__ __launch_bounds__(256) void k_e1_t(const float* __restrict__ X, const float* __restrict__ Wt,
                                              const float* __restrict__ Wp, const float* __restrict__ bt,
                                              const float* __restrict__ bp, float* __restrict__ m,
                                              float* __restrict__ pbuf, int N) {
    __shared__ float Wl[64 * 128];
    __shared__ float Xs[64 * 65];
    int t = threadIdx.x;
    for (int idx = t; idx < 64 * 64; idx += 256) {
        int k = idx >> 6, c = idx & 63;
        float wt = Wt[idx];
        Wl[k * 128 + c] = wt;
        Wl[k * 128 + 64 + c] = wt + Wp[idx];
    }

    int nbase = blockIdx.x * 64;
    int ln0 = t & 31, ln1 = 32 + ln0;
    int c0 = (t >> 5) * 16;      // 16 cols in [0,128)

    int sn = t & 63;
    int sk0 = (t >> 6) * 16;
    int gn = nbase + sn; if (gn >= N) gn = N - 1;
#pragma unroll
    for (int i = 0; i < 4; ++i) {
        float4 v = *(const float4*)&X[(size_t)gn * 64 + sk0 + 4 * i];
        Xs[(sk0 + 4 * i + 0) * 65 + sn] = v.x;
        Xs[(sk0 + 4 * i + 1) * 65 + sn] = v.y;
        Xs[(sk0 + 4 * i + 2) * 65 + sn] = v.z;
        Xs[(sk0 + 4 * i + 3) * 65 + sn] = v.w;
    }
    __syncthreads();

    float a0[16], a1[16];
#pragma unroll
    for (int i = 0; i < 16; ++i) { a0[i] = 0.f; a1[i] = 0.f; }

#pragma unroll 2
    for (int k = 0; k < 64; ++k) {
        float x0 = Xs[k * 65 + ln0];
        float x1 = Xs[k * 65 + ln1];
        const float4* wr = (const float4*)&Wl[k * 128 + c0];
#pragma unroll
        for (int q = 0; q < 4; ++q) {
            float4 w = wr[q];
            a0[4 * q + 0] += x0 * w.x; a0[4 * q + 1] += x0 * w.y; a0[4 * q + 2] += x0 * w.z; a0[4 * q + 3] += x0 * w.w;
            a1[4 * q + 0] += x1 * w.x; a1[4 * q + 1] += x1 * w.y; a1[4 * q + 2] += x1 * w.z; a1[4 * q + 3] += x1 * w.w;
        }
    }

    int n0 = nbase + ln0, n1 = nbase + ln1;
    if (c0 < 64) {               // this band -> m (no bias)
        if (n0 < N) {
#pragma unroll
            for (int q = 0; q < 4; ++q) {
                float4 r = { a0[4 * q], a0[4 * q + 1], a0[4 * q + 2], a0[4 * q + 3] };
                *(float4*)&m[(size_t)n0 * 64 + c0 + 4 * q] = r;
            }
        }
        if (n1 < N) {
#pragma unroll
            for (int q = 0; q < 4; ++q) {
                float4 r = { a1[4 * q], a1[4 * q + 1], a1[4 * q + 2], a1[4 * q + 3] };
                *(float4*)&m[(size_t)n1 * 64 + c0 + 4 * q] = r;
            }
        }
    } else {                     // this band -> pbuf (+ bias)
        int cc = c0 - 64;
        float bb[16];
#pragma unroll
        for (int i = 0; i < 16; ++i) bb[i] = bt[cc + i] + bp[cc + i];
        if (n0 < N) {
#pragma unroll
            for (int q = 0; q < 4; ++q) {
                float4 r = { a0[4 * q] + bb[4 * q], a0[4 * q + 1] + bb[4 * q + 1], a0[4 * q + 2] + bb[4 * q + 2], a0[4 * q + 3] + bb[4 * q + 3] };
                *(float4*)&pbuf[(size_t)n0 * 64 + cc + 4 * q] = r;
            }
        }
        if (n1 < N) {
#pragma unroll
            for (int q = 0; q < 4; ++q) {
                float4 r = { a1[4 * q] + bb[4 * q], a1[4 * q + 1] + bb[4 * q + 1], a1[4 * q + 2] + bb[4 * q + 2], a1[4 * q + 3] + bb[4 * q + 3] };
                *(float4*)&pbuf[(size_t)n1 * 64 + cc + 4 * q] = r;
            }
        }
    }
}

// ---------------- EdgeConv stage 2: out = relu(p[n] + max_j(-m[src_j])), 0 if no in-edges ----------------

__global__ __launch_bounds__(256) void k_e2(const float* __restrict__ m, const float* __restrict__ pbuf,
                                            const int* __restrict__ row_off, const int* __restrict__ csr,
                                            float* __restrict__ out, int N) {
    int t = blockIdx.x * blockDim.x + threadIdx.x;
    int node = t >> 6;
    int d = t & 63;
    if (node >= N) return;
    int beg = row_off[node], end = row_off[node + 1];
    float a0 = -INFINITY, a1 = -INFINITY, a2 = -INFINITY, a3 = -INFINITY;
    int j = beg;
    for (; j + 3 < end; j += 4) {
        int s0 = csr[j], s1 = csr[j + 1], s2 = csr[j + 2], s3 = csr[j + 3];
        a0 = fmaxf(a0, -m[s0 * 64 + d]);
        a1 = fmaxf(a1, -m[s1 * 64 + d]);
        a2 = fmaxf(a2, -m[s2 * 64 + d]);
        a3 = fmaxf(a3, -m[s3 * 64 + d]);
    }
    for (; j < end; ++j) {
        int s = csr[j];
        a0 = fmaxf(a0, -m[s * 64 + d]);
    }
    float r = 0.f;
    if (end > beg) r = fmaxf(pbuf[node * 64 + d] + fmaxf(fmaxf(a0, a1), fmaxf(a2, a3)), 0.f);
    out[node * 64 + d] = r;
}

// ---------------- graph mean pooling (segmented: gid is sorted) ----------------

__global__ __launch_bounds__(256) void k_pool(const float* __restrict__ h, const int* __restrict__ gid,
                                              float* __restrict__ out, float* __restrict__ gcnt, int N) {
    const int CHUNK = 128;
    int wave = blockIdx.x * 4 + (threadIdx.x >> 6);
    int lane = threadIdx.x & 63;
    int beg = wave * CHUNK;
    if (beg >= N) return;
    int end = beg + CHUNK < N ? beg + CHUNK : N;
    int gcur = gid[beg];
    float acc = 0.f;
    int cnt = 0;
    for (int n = beg; n < end; ++n) {
        int g = gid[n];
        float v = h[n * 64 + lane];
        if (g != gcur) {
            atomicAdd(&out[gcur * 64 + lane], acc);
            if (lane == 0) atomicAdd(&gcnt[gcur], (float)cnt);
            gcur = g; acc = 0.f; cnt = 0;
        }
        acc += v;
        ++cnt;
    }
    atomicAdd(&out[gcur * 64 + lane], acc);
    if (lane == 0) atomicAdd(&gcnt[gcur], (float)cnt);
}

__global__ __launch_bounds__(256) void k_div(float* __restrict__ out, const float* __restrict__ gcnt, int total) {
    int i = blockIdx.x * blockDim.x + threadIdx.x;
    if (i < total) out[i] /= fmaxf(gcnt[i >> 6], 1.f);
}

// ---------------- launcher ----------------

extern "C" void kernel_launch(void* const* d_in, const int* in_sizes, int n_in,
                              void* d_out, int out_size, void* d_ws, size_t ws_size,
                              hipStream_t stream) {
    const float* feat = (const float*)d_in[0];
    const int* src = (const int*)d_in[1];
    const int* dst = (const int*)d_in[2];
    const int* gid = (const int*)d_in[3];
    const float* W1 = (const float*)d_in[4];  const float* b1 = (const float*)d_in[5];
    const float* W2 = (const float*)d_in[6];  const float* b2 = (const float*)d_in[7];
    const float* W3 = (const float*)d_in[8];  const float* b3 = (const float*)d_in[9];
    const float* Wt1 = (const float*)d_in[10]; const float* bt1 = (const float*)d_in[11];
    const float* Wp1 = (const float*)d_in[12]; const float* bp1 = (const float*)d_in[13];
    const float* Wt2 = (const float*)d_in[14]; const float* bt2 = (const float*)d_in[15];
    const float* Wp2 = (const float*)d_in[16]; const float* bp2 = (const float*)d_in[17];
    float* out = (float*)d_out;

    const int N = in_sizes[0] / 16;
    const int E = in_sizes[1];
    const int G = out_size / 64;

    char* p = (char*)d_ws;
    auto alloc = [&](size_t nbytes) {
        void* r = (void*)p;
        p += (nbytes + 255) & ~(size_t)255;
        return r;
    };
    int* cnt      = (int*)alloc((size_t)N * 4);
    int* row_off  = (int*)alloc((size_t)(N + 1) * 4);
    int* cursor   = (int*)alloc((size_t)N * 4);
    int* csr      = (int*)alloc((size_t)E * 4);
    int* bsum     = (int*)alloc(512 * 4);
    float* dinv   = (float*)alloc((size_t)N * 4);
    float* bufA   = (float*)alloc((size_t)N * 64 * 4);
    float* bufB   = (float*)alloc((size_t)N * 64 * 4);
    float* bufC   = (float*)alloc((size_t)N * 64 * 4);
    float* bufD   = (float*)alloc((size_t)N * 64 * 4);
    float* gcnt   = (float*)alloc((size_t)G * 4);

    hipMemsetAsync(cnt, 0, (size_t)N * 4, stream);
    hipMemsetAsync(gcnt, 0, (size_t)G * 4, stream);
    hipMemsetAsync(d_out, 0, (size_t)out_size * 4, stream);

    const int B = (N + 255) / 256;
    const int ebk = (E + 255) / 256;
    const int nb64 = (N * 64 + 255) / 256;
    const int nb16 = (N * 16 + 255) / 256;
    const int npool = ((N + 127) / 128 + 3) / 4;
    const int nbt = (N + 63) / 64;     // tiled GEMM blocks

    k_hist<<<ebk, 256, 0, stream>>>(dst, cnt, E);
    k_scanA<<<B, 256, 0, stream>>>(cnt, bsum, N);
    k_scanB<<<1, 512, 0, stream>>>(bsum, B);
    k_scanC<<<B, 256, 0, stream>>>(cnt, bsum, row_off, cursor, dinv, N, E);
    k_scatter<<<ebk, 256, 0, stream>>>(src, dst, cursor, csr, E);

    // ---- Cheb layer 1 (IN=16) : X1 = -aggr(X0); X2 = -2*aggr(X1) - X0
    k_aggr<16><<<nb16, 256, 0, stream>>>(feat, nullptr, dinv, row_off, csr, bufA, -1.f, 0.f, N);
    k_aggr<16><<<nb16, 256, 0, stream>>>(bufA, feat, dinv, row_off, csr, bufB, -2.f, -1.f, N);
    k_cheb_t<16><<<nbt, 256, 0, stream>>>(feat, bufA, bufB, W1, b1, bufC, N);

    // ---- EdgeConv 1
    k_e1_t<<<nbt, 256, 0, stream>>>(bufC, Wt1, Wp1, bt1, bp1, bufA, bufB, N);
    k_e2<<<nb64, 256, 0, stream>>>(bufA, bufB, row_off, csr, bufD, N);

    // ---- Cheb layer 2
    k_aggr<64><<<nb64, 256, 0, stream>>>(bufD, nullptr, dinv, row_off, csr, bufA, -1.f, 0.f, N);
    k_aggr<64><<<nb64, 256, 0, stream>>>(bufA, bufD, dinv, row_off, csr, bufB, -2.f, -1.f, N);
    k_cheb_t<64><<<nbt, 256, 0, stream>>>(bufD, bufA, bufB, W2, b2, bufC, N);

    // ---- EdgeConv 2
    k_e1_t<<<nbt, 256, 0, stream>>>(bufC, Wt2, Wp2, bt2, bp2, bufA, bufB, N);
    k_e2<<<nb64, 256, 0, stream>>>(bufA, bufB, row_off, csr, bufD, N);

    // ---- Cheb layer 3
    k_aggr<64><<<nb64, 256, 0, stream>>>(bufD, nullptr, dinv, row_off, csr, bufA, -1.f, 0.f, N);
    k_aggr<64><<<nb64, 256, 0, stream>>>(bufA, bufD, dinv, row_off, csr, bufB, -2.f, -1.f, N);
    k_cheb_t<64><<<nbt, 256, 0, stream>>>(bufD, bufA, bufB, W3, b3, bufC, N);

    // ---- per-graph mean pooling
    k_pool<<<npool, 256, 0, stream>>>(bufC, gid, out, gcnt, N);
    k_div<<<(out_size + 255) / 256, 256, 0, stream>>>(out, gcnt, out_size);
}